// Round 2
// baseline (2567.656 us; speedup 1.0000x reference)
//
#include <hip/hip_runtime.h>
#include <hip/hip_bf16.h>

#define N_PTS  65536
#define DMODEL 256
#define MSAMP  1024

#define FW  16   // FPS workgroups (all co-resident; 16 << 256 CUs)
#define FPT 16   // points per FPS thread: 65536 / (16 * 256)

typedef short bf16x8_t __attribute__((ext_vector_type(8)));
typedef float f32x4_t  __attribute__((ext_vector_type(4)));

__device__ __forceinline__ short f2bs(float f) {
    __hip_bfloat16 h = __float2bfloat16(f);   // RNE
    return *reinterpret_cast<short*>(&h);
}

// load 8 consecutive f32 and convert to a bf16x8 MFMA fragment
__device__ __forceinline__ bf16x8_t cvt8(const float* p) {
    f32x4_t a = *(const f32x4_t*)(p);
    f32x4_t b = *(const f32x4_t*)(p + 4);
    bf16x8_t r;
#pragma unroll
    for (int i = 0; i < 4; i++) {
        r[i]     = f2bs(a[i]);
        r[i + 4] = f2bs(b[i]);
    }
    return r;
}

// ---------------------------------------------------------------------------
// FPS: 16 workgroups, dists+coords in registers, per-iteration packed
// atomicMax argmax + release/acquire counter barrier. Exact f32 arithmetic
// (no contraction) and first-index tie-break to match the numpy reference.
// ---------------------------------------------------------------------------
__global__ __launch_bounds__(256) void fps_kernel(
    const float*        __restrict__ xyz,      // (N,3) f32
    unsigned long long* __restrict__ slots,    // (MSAMP) zeroed
    unsigned*           __restrict__ cnt,      // (MSAMP) zeroed
    int*                __restrict__ idx)      // (MSAMP) out
{
    const int t = threadIdx.x;
    const int g = blockIdx.x;
    __shared__ unsigned long long wred[4];
    __shared__ int curs;

    float px[FPT], py[FPT], pz[FPT], dd[FPT];
    const int pid0 = g * (FPT * 256) + t;
#pragma unroll
    for (int i = 0; i < FPT; i++) {
        int p = pid0 + i * 256;
        px[i] = xyz[3 * p + 0];
        py[i] = xyz[3 * p + 1];
        pz[i] = xyz[3 * p + 2];
        dd[i] = 1e10f;
    }
    if (g == 0 && t == 0) idx[0] = 0;

    int cur = 0;
    for (int it = 1; it < MSAMP; it++) {
        float cx = xyz[3 * cur + 0];
        float cy = xyz[3 * cur + 1];
        float cz = xyz[3 * cur + 2];
        float vmax = -1.0f;
        int   imax = pid0;
#pragma unroll
        for (int i = 0; i < FPT; i++) {
            float dx = __fsub_rn(px[i], cx);
            float dy = __fsub_rn(py[i], cy);
            float dz = __fsub_rn(pz[i], cz);
            // numpy order: ((dx^2 + dy^2) + dz^2), each op rounded f32, no FMA
            float d  = __fadd_rn(__fadd_rn(__fmul_rn(dx, dx), __fmul_rn(dy, dy)),
                                 __fmul_rn(dz, dz));
            float nd = fminf(dd[i], d);
            dd[i] = nd;
            if (nd > vmax) { vmax = nd; imax = pid0 + i * 256; }  // strict >: first max in-thread
        }
        // pack: f32 bits high (non-negative -> monotone as u32), ~idx low
        // (max of packs == max value; ties resolve to smallest index, numpy-style)
        unsigned long long pack =
            (((unsigned long long)__float_as_uint(vmax)) << 32) |
            (unsigned)(~(unsigned)imax);
#pragma unroll
        for (int off = 32; off > 0; off >>= 1) {
            unsigned long long o = __shfl_down(pack, off, 64);
            if (o > pack) pack = o;
        }
        if ((t & 63) == 0) wred[t >> 6] = pack;
        __syncthreads();
        if (t == 0) {
            unsigned long long bp = wred[0];
            if (wred[1] > bp) bp = wred[1];
            if (wred[2] > bp) bp = wred[2];
            if (wred[3] > bp) bp = wred[3];
            atomicMax(&slots[it], bp);
            __hip_atomic_fetch_add(&cnt[it], 1u, __ATOMIC_RELEASE,
                                   __HIP_MEMORY_SCOPE_AGENT);
            while (__hip_atomic_load(&cnt[it], __ATOMIC_ACQUIRE,
                                     __HIP_MEMORY_SCOPE_AGENT) < (unsigned)FW) {
                __builtin_amdgcn_s_sleep(2);
            }
            unsigned long long wwin = __hip_atomic_load(
                &slots[it], __ATOMIC_RELAXED, __HIP_MEMORY_SCOPE_AGENT);
            int widx = (int)(~(unsigned)wwin);
            curs = widx;
            if (g == 0) idx[it] = widx;
        }
        __syncthreads();
        cur = curs;
    }
}

// ---------------------------------------------------------------------------
// Gather + K/V projection in f32; outputs bf16. k is pre-scaled by 1/16
// (exact power of 2) and stored row-major (j,k); v stored transposed (d,j).
// ---------------------------------------------------------------------------
__global__ __launch_bounds__(256) void kv_kernel(
    const float* __restrict__ feat,
    const float* __restrict__ Wk, const float* __restrict__ bk,
    const float* __restrict__ Wv, const float* __restrict__ bv,
    const int* __restrict__ idx,
    unsigned short* __restrict__ k_s,   // (MSAMP, DMODEL) bf16, * 1/16
    unsigned short* __restrict__ vT)    // (DMODEL, MSAMP) bf16
{
    __shared__ float fl[4][DMODEL];
    const int t  = threadIdx.x;
    const int j0 = blockIdx.x * 4;
    {
        int jj = t >> 6;
        int e  = (t & 63) * 4;
        int src = idx[j0 + jj];
        f32x4_t v = *(const f32x4_t*)(feat + (size_t)src * DMODEL + e);
        fl[jj][e + 0] = v[0];
        fl[jj][e + 1] = v[1];
        fl[jj][e + 2] = v[2];
        fl[jj][e + 3] = v[3];
    }
    __syncthreads();

    float ak[4] = {0.f, 0.f, 0.f, 0.f};
    float av[4] = {0.f, 0.f, 0.f, 0.f};
    const float* wkr = Wk + (size_t)t * DMODEL;
    const float* wvr = Wv + (size_t)t * DMODEL;
#pragma unroll 4
    for (int in = 0; in < DMODEL; in += 4) {
        f32x4_t ku = *(const f32x4_t*)(wkr + in);
        f32x4_t vu = *(const f32x4_t*)(wvr + in);
#pragma unroll
        for (int jj = 0; jj < 4; jj++) {
            ak[jj] = fmaf(fl[jj][in + 0], ku[0], ak[jj]);
            ak[jj] = fmaf(fl[jj][in + 1], ku[1], ak[jj]);
            ak[jj] = fmaf(fl[jj][in + 2], ku[2], ak[jj]);
            ak[jj] = fmaf(fl[jj][in + 3], ku[3], ak[jj]);
            av[jj] = fmaf(fl[jj][in + 0], vu[0], av[jj]);
            av[jj] = fmaf(fl[jj][in + 1], vu[1], av[jj]);
            av[jj] = fmaf(fl[jj][in + 2], vu[2], av[jj]);
            av[jj] = fmaf(fl[jj][in + 3], vu[3], av[jj]);
        }
    }
    float bkv = bk[t];
    float bvv = bv[t];
#pragma unroll
    for (int jj = 0; jj < 4; jj++) {
        k_s[(unsigned)(j0 + jj) * DMODEL + t] = (unsigned short)f2bs((ak[jj] + bkv) * 0.0625f);
        vT[(unsigned)t * MSAMP + (j0 + jj)]   = (unsigned short)f2bs(av[jj] + bvv);
    }
}

// ---------------------------------------------------------------------------
// Fused q -> w -> res -> concat. 128-row tile per WG, 4 waves (2 row x 2 col),
// MFMA 16x16x32 bf16 (f32 inputs converted inline). Epilogue stages f32 res
// in LDS and writes coalesced f32 [res | features].
// ---------------------------------------------------------------------------
#define QS  264   // qlds row stride (bf16), pad kills 512B-stride conflicts
#define WSR 136   // wlds row stride (bf16)
#define RS  258   // rlds row stride (f32): 4*258 mod 32banks -> shift 8/row-group
#define MAIN_LDS (128 * RS * 4)   // 132096 B (>= phase-1/2 usage of 102400 B)

__global__ __launch_bounds__(256, 1) void main_kernel(
    const float* __restrict__ feat,
    const float* __restrict__ Wq, const float* __restrict__ bq,
    const unsigned short* __restrict__ k_s,
    const unsigned short* __restrict__ vT,
    float* __restrict__ out)
{
    extern __shared__ char smem[];
    unsigned short* qlds = (unsigned short*)smem;
    unsigned short* wlds = (unsigned short*)(smem + 128 * QS * 2);

    const int tid  = threadIdx.x;
    const int ln   = tid & 63;
    const int wid  = tid >> 6;
    const int wr   = wid & 1;
    const int wc   = wid >> 1;
    const int r0   = blockIdx.x * 128;
    const int lrow = ln & 15;
    const int lk   = (ln >> 4) * 8;
    const int crow = (ln >> 4) * 4;

    const f32x4_t fzero = {0.f, 0.f, 0.f, 0.f};

    // ---- phase 1: q = feat @ Wq^T + bq -> bf16 in qlds ----
    f32x4_t qa[4][8];
#pragma unroll
    for (int m = 0; m < 4; m++)
#pragma unroll
        for (int n = 0; n < 8; n++) qa[m][n] = fzero;

#pragma unroll
    for (int kb = 0; kb < DMODEL; kb += 32) {
        bf16x8_t A[4], B[8];
#pragma unroll
        for (int m = 0; m < 4; m++)
            A[m] = cvt8(feat + (size_t)(r0 + wr * 64 + m * 16 + lrow) * DMODEL + kb + lk);
#pragma unroll
        for (int n = 0; n < 8; n++)
            B[n] = cvt8(Wq + (size_t)(wc * 128 + n * 16 + lrow) * DMODEL + kb + lk);
#pragma unroll
        for (int m = 0; m < 4; m++)
#pragma unroll
            for (int n = 0; n < 8; n++)
                qa[m][n] = __builtin_amdgcn_mfma_f32_16x16x32_bf16(
                    A[m], B[n], qa[m][n], 0, 0, 0);
    }
#pragma unroll
    for (int n = 0; n < 8; n++) {
        float bqv = bq[wc * 128 + n * 16 + lrow];
#pragma unroll
        for (int m = 0; m < 4; m++)
#pragma unroll
            for (int r = 0; r < 4; r++)
                qlds[(wr * 64 + m * 16 + crow + r) * QS + wc * 128 + n * 16 + lrow] =
                    (unsigned short)f2bs(qa[m][n][r] + bqv);
    }
    __syncthreads();

    // ---- phase 2: flash-style w-chunk -> res accumulation ----
    f32x4_t racc[4][8];
#pragma unroll
    for (int m = 0; m < 4; m++)
#pragma unroll
        for (int n = 0; n < 8; n++) racc[m][n] = fzero;

    for (int jb = 0; jb < 8; jb++) {
        f32x4_t wa[4][4];
#pragma unroll
        for (int m = 0; m < 4; m++)
#pragma unroll
            for (int n = 0; n < 4; n++) wa[m][n] = fzero;

#pragma unroll
        for (int kb = 0; kb < DMODEL; kb += 32) {
            bf16x8_t A[4], B[4];
#pragma unroll
            for (int m = 0; m < 4; m++)
                A[m] = *(const bf16x8_t*)(qlds +
                    (wr * 64 + m * 16 + lrow) * QS + kb + lk);
#pragma unroll
            for (int n = 0; n < 4; n++)
                B[n] = *(const bf16x8_t*)(k_s +
                    (size_t)(jb * 128 + wc * 64 + n * 16 + lrow) * DMODEL + kb + lk);
#pragma unroll
            for (int m = 0; m < 4; m++)
#pragma unroll
                for (int n = 0; n < 4; n++)
                    wa[m][n] = __builtin_amdgcn_mfma_f32_16x16x32_bf16(
                        A[m], B[n], wa[m][n], 0, 0, 0);
        }
#pragma unroll
        for (int m = 0; m < 4; m++)
#pragma unroll
            for (int n = 0; n < 4; n++)
#pragma unroll
                for (int r = 0; r < 4; r++)
                    wlds[(wr * 64 + m * 16 + crow + r) * WSR + wc * 64 + n * 16 + lrow] =
                        (unsigned short)f2bs(wa[m][n][r]);
        __syncthreads();

#pragma unroll
        for (int kb2 = 0; kb2 < 128; kb2 += 32) {
            bf16x8_t A[4], B[8];
#pragma unroll
            for (int m = 0; m < 4; m++)
                A[m] = *(const bf16x8_t*)(wlds +
                    (wr * 64 + m * 16 + lrow) * WSR + kb2 + lk);
#pragma unroll
            for (int n = 0; n < 8; n++)
                B[n] = *(const bf16x8_t*)(vT +
                    (size_t)(wc * 128 + n * 16 + lrow) * MSAMP + jb * 128 + kb2 + lk);
#pragma unroll
            for (int m = 0; m < 4; m++)
#pragma unroll
                for (int n = 0; n < 8; n++)
                    racc[m][n] = __builtin_amdgcn_mfma_f32_16x16x32_bf16(
                        A[m], B[n], racc[m][n], 0, 0, 0);
        }
        __syncthreads();
    }

    // ---- phase 3: epilogue, f32 res -> LDS, coalesced f32 [res|feat] store ----
    float* rlds = (float*)smem;   // qlds/wlds dead now
#pragma unroll
    for (int m = 0; m < 4; m++)
#pragma unroll
        for (int n = 0; n < 8; n++)
#pragma unroll
            for (int r = 0; r < 4; r++)
                rlds[(wr * 64 + m * 16 + crow + r) * RS + wc * 128 + n * 16 + lrow] =
                    racc[m][n][r];
    __syncthreads();

#pragma unroll
    for (int base = 0; base < 128; base += 4) {
        int row = base + wid;
        f32x4_t a = *(const f32x4_t*)(rlds + row * RS + ln * 4);
        f32x4_t b = *(const f32x4_t*)(feat + (size_t)(r0 + row) * DMODEL + ln * 4);
        *(f32x4_t*)(out + (size_t)(r0 + row) * 512 + ln * 4)       = a;
        *(f32x4_t*)(out + (size_t)(r0 + row) * 512 + 256 + ln * 4) = b;
    }
}

// ---------------------------------------------------------------------------
extern "C" void kernel_launch(void* const* d_in, const int* in_sizes, int n_in,
                              void* d_out, int out_size, void* d_ws, size_t ws_size,
                              hipStream_t stream) {
    const float* p_xyz = (const float*)d_in[0];
    const float* feat  = (const float*)d_in[1];
    const float* Wq    = (const float*)d_in[2];
    const float* bq    = (const float*)d_in[3];
    const float* Wk    = (const float*)d_in[4];
    const float* bk    = (const float*)d_in[5];
    const float* Wv    = (const float*)d_in[6];
    const float* bv    = (const float*)d_in[7];
    float* out = (float*)d_out;

    char* ws = (char*)d_ws;
    unsigned long long* slots = (unsigned long long*)ws;                //   8 KB
    unsigned*           cnt   = (unsigned*)(ws + 8192);                 //   4 KB
    int*                idx   = (int*)(ws + 12288);                     //   4 KB
    unsigned short*     k_s   = (unsigned short*)(ws + 16384);          // 512 KB
    unsigned short*     vT    = (unsigned short*)(ws + 16384 + 524288); // 512 KB

    hipMemsetAsync(d_ws, 0, 12288, stream);   // slots + cnt fresh every call

    hipLaunchKernelGGL(fps_kernel, dim3(FW), dim3(256), 0, stream,
                       p_xyz, slots, cnt, idx);
    hipLaunchKernelGGL(kv_kernel, dim3(MSAMP / 4), dim3(256), 0, stream,
                       feat, Wk, bk, Wv, bv, idx, k_s, vT);
    hipFuncSetAttribute((const void*)main_kernel,
                        hipFuncAttributeMaxDynamicSharedMemorySize, MAIN_LDS);
    hipLaunchKernelGGL(main_kernel, dim3(N_PTS / 128), dim3(256), MAIN_LDS, stream,
                       feat, Wq, bq, k_s, vT, out);
}

// Round 3
// 2352.037 us; speedup vs baseline: 1.0917x; 1.0917x over previous
//
#include <hip/hip_runtime.h>
#include <hip/hip_bf16.h>

#define N_PTS  65536
#define DMODEL 256
#define MSAMP  1024

#define NW  64   // FPS waves = single-wave workgroups (all co-resident; 64 << 256 CUs)
#define FPT 16   // points per lane: 65536 / (64 * 64)

typedef short bf16x8_t __attribute__((ext_vector_type(8)));
typedef float f32x4_t  __attribute__((ext_vector_type(4)));

__device__ __forceinline__ short f2bs(float f) {
    __hip_bfloat16 h = __float2bfloat16(f);   // RNE
    return *reinterpret_cast<short*>(&h);
}

// load 8 consecutive f32 and convert to a bf16x8 MFMA fragment
__device__ __forceinline__ bf16x8_t cvt8(const float* p) {
    f32x4_t a = *(const f32x4_t*)(p);
    f32x4_t b = *(const f32x4_t*)(p + 4);
    bf16x8_t r;
#pragma unroll
    for (int i = 0; i < 4; i++) {
        r[i]     = f2bs(a[i]);
        r[i + 4] = f2bs(b[i]);
    }
    return r;
}

// ---------------------------------------------------------------------------
// FPS: 64 single-wave blocks. Per iteration: in-register min-update + argmax,
// 6-step shfl butterfly (packs compared as positive f64 bit patterns), ONE
// relaxed agent-scope 32B slot store (candidate pack + candidate coords, each
// u64 tagged with the iteration), then all lanes poll the 64 slots and
// butterfly-reduce the global winner. Winner coords arrive via shfl from the
// slot — no dependent xyz[cur] reload, no atomics, no LDS, no __syncthreads.
// Slots are double-buffered by iteration parity (2-phase safe).
// Exact numpy arithmetic: per-op RN f32, ((dx^2+dy^2)+dz^2), first-index
// argmax tie-break via (value, 0xFFFF-idx) packing.
// ---------------------------------------------------------------------------
__global__ __launch_bounds__(64) void fps_kernel(
    const float*        __restrict__ xyz,      // (N,3) f32
    unsigned long long* __restrict__ slots,    // [2][NW][4] u64, zeroed per call
    int*                __restrict__ idx)      // (MSAMP) out
{
    const int l = threadIdx.x;       // 0..63
    const int g = blockIdx.x;        // 0..63
    const int base = g * (FPT * 64) + l;

    float px[FPT], py[FPT], pz[FPT], dd[FPT];
#pragma unroll
    for (int i = 0; i < FPT; i++) {
        int p = base + i * 64;
        px[i] = xyz[3 * p + 0];
        py[i] = xyz[3 * p + 1];
        pz[i] = xyz[3 * p + 2];
        dd[i] = 1e10f;
    }
    if (g == 0 && l == 0) idx[0] = 0;

    float cx = xyz[0], cy = xyz[1], cz = xyz[2];   // centroid 0 = point 0

    for (int it = 1; it < MSAMP; ++it) {
        // ---- local min-update + argmax (tracks winning coords in-register) --
        float vmax = -1.0f, bx = 0.f, by = 0.f, bz = 0.f;
        int   imax = 0;
#pragma unroll
        for (int i = 0; i < FPT; i++) {
            float dx = __fsub_rn(px[i], cx);
            float dy = __fsub_rn(py[i], cy);
            float dz = __fsub_rn(pz[i], cz);
            float d  = __fadd_rn(__fadd_rn(__fmul_rn(dx, dx), __fmul_rn(dy, dy)),
                                 __fmul_rn(dz, dz));
            float nd = fminf(dd[i], d);
            dd[i] = nd;
            bool c = nd > vmax;                 // strict >: keeps smallest idx
            vmax = c ? nd    : vmax;
            imax = c ? (base + i * 64) : imax;
            bx   = c ? px[i] : bx;
            by   = c ? py[i] : by;
            bz   = c ? pz[i] : bz;
        }
        // pack: f32 bits high (non-neg -> monotone), tag mid, ~idx low.
        unsigned long long pack =
            (((unsigned long long)__float_as_uint(vmax)) << 32) |
            (((unsigned long long)(unsigned)it) << 16) |
            (unsigned long long)(0xFFFFu - (unsigned)imax);

        // ---- in-wave butterfly (positive f64 bit patterns: fmax == u64 max)
        double dp = __longlong_as_double((long long)pack);
#pragma unroll
        for (int s = 1; s < 64; s <<= 1)
            dp = fmax(dp, __shfl_xor(dp, s, 64));
        unsigned long long wbest = (unsigned long long)__double_as_longlong(dp);

        // owner lane -> wave-candidate coords to all lanes
        unsigned long long mo = __ballot(pack == wbest);
        int ol = __ffsll((unsigned long long)mo) - 1;
        float wx = __shfl(bx, ol, 64);
        float wy = __shfl(by, ol, 64);
        float wz = __shfl(bz, ol, 64);

        // ---- publish slot (4 lanes store 4 tagged u64s, coalesced 32B) -----
        const int ph = it & 1;
        unsigned long long sv = wbest;
        unsigned long long xp = (((unsigned long long)__float_as_uint(wx)) << 32) | (unsigned)it;
        unsigned long long yp = (((unsigned long long)__float_as_uint(wy)) << 32) | (unsigned)it;
        unsigned long long zp = (((unsigned long long)__float_as_uint(wz)) << 32) | (unsigned)it;
        sv = (l == 1) ? xp : sv;
        sv = (l == 2) ? yp : sv;
        sv = (l == 3) ? zp : sv;
        if (l < 4)
            __hip_atomic_store(slots + ((size_t)(ph * NW + g) * 4 + l), sv,
                               __ATOMIC_RELAXED, __HIP_MEMORY_SCOPE_AGENT);

        // ---- poll all NW slots (lane L -> slot L), tag-validated ----------
        const unsigned long long* Q = slots + (size_t)ph * NW * 4;
        unsigned long long u0, u1, u2, u3;
        for (;;) {
            u0 = __hip_atomic_load(Q + l * 4 + 0, __ATOMIC_RELAXED, __HIP_MEMORY_SCOPE_AGENT);
            u1 = __hip_atomic_load(Q + l * 4 + 1, __ATOMIC_RELAXED, __HIP_MEMORY_SCOPE_AGENT);
            u2 = __hip_atomic_load(Q + l * 4 + 2, __ATOMIC_RELAXED, __HIP_MEMORY_SCOPE_AGENT);
            u3 = __hip_atomic_load(Q + l * 4 + 3, __ATOMIC_RELAXED, __HIP_MEMORY_SCOPE_AGENT);
            bool ok = (((unsigned)(u0 >> 16) & 0xFFFFu) == (unsigned)it) &
                      ((unsigned)u1 == (unsigned)it) &
                      ((unsigned)u2 == (unsigned)it) &
                      ((unsigned)u3 == (unsigned)it);
            if (__all(ok)) break;
        }

        // ---- global winner butterfly + coords via shfl --------------------
        double gp = __longlong_as_double((long long)u0);
#pragma unroll
        for (int s = 1; s < 64; s <<= 1)
            gp = fmax(gp, __shfl_xor(gp, s, 64));
        unsigned long long gbest = (unsigned long long)__double_as_longlong(gp);
        int win = 0xFFFF - (int)(gbest & 0xFFFFu);

        unsigned long long mw = __ballot(u0 == gbest);
        int wl = __ffsll((unsigned long long)mw) - 1;
        cx = __shfl(__uint_as_float((unsigned)(u1 >> 32)), wl, 64);
        cy = __shfl(__uint_as_float((unsigned)(u2 >> 32)), wl, 64);
        cz = __shfl(__uint_as_float((unsigned)(u3 >> 32)), wl, 64);

        if (g == 0 && l == 0) idx[it] = win;
    }
}

// ---------------------------------------------------------------------------
// Gather + K/V projection in f32; outputs bf16. k is pre-scaled by 1/16
// (exact power of 2) and stored row-major (j,k); v stored transposed (d,j).
// ---------------------------------------------------------------------------
__global__ __launch_bounds__(256) void kv_kernel(
    const float* __restrict__ feat,
    const float* __restrict__ Wk, const float* __restrict__ bk,
    const float* __restrict__ Wv, const float* __restrict__ bv,
    const int* __restrict__ idx,
    unsigned short* __restrict__ k_s,   // (MSAMP, DMODEL) bf16, * 1/16
    unsigned short* __restrict__ vT)    // (DMODEL, MSAMP) bf16
{
    __shared__ float fl[4][DMODEL];
    const int t  = threadIdx.x;
    const int j0 = blockIdx.x * 4;
    {
        int jj = t >> 6;
        int e  = (t & 63) * 4;
        int src = idx[j0 + jj];
        f32x4_t v = *(const f32x4_t*)(feat + (size_t)src * DMODEL + e);
        fl[jj][e + 0] = v[0];
        fl[jj][e + 1] = v[1];
        fl[jj][e + 2] = v[2];
        fl[jj][e + 3] = v[3];
    }
    __syncthreads();

    float ak[4] = {0.f, 0.f, 0.f, 0.f};
    float av[4] = {0.f, 0.f, 0.f, 0.f};
    const float* wkr = Wk + (size_t)t * DMODEL;
    const float* wvr = Wv + (size_t)t * DMODEL;
#pragma unroll 4
    for (int in = 0; in < DMODEL; in += 4) {
        f32x4_t ku = *(const f32x4_t*)(wkr + in);
        f32x4_t vu = *(const f32x4_t*)(wvr + in);
#pragma unroll
        for (int jj = 0; jj < 4; jj++) {
            ak[jj] = fmaf(fl[jj][in + 0], ku[0], ak[jj]);
            ak[jj] = fmaf(fl[jj][in + 1], ku[1], ak[jj]);
            ak[jj] = fmaf(fl[jj][in + 2], ku[2], ak[jj]);
            ak[jj] = fmaf(fl[jj][in + 3], ku[3], ak[jj]);
            av[jj] = fmaf(fl[jj][in + 0], vu[0], av[jj]);
            av[jj] = fmaf(fl[jj][in + 1], vu[1], av[jj]);
            av[jj] = fmaf(fl[jj][in + 2], vu[2], av[jj]);
            av[jj] = fmaf(fl[jj][in + 3], vu[3], av[jj]);
        }
    }
    float bkv = bk[t];
    float bvv = bv[t];
#pragma unroll
    for (int jj = 0; jj < 4; jj++) {
        k_s[(unsigned)(j0 + jj) * DMODEL + t] = (unsigned short)f2bs((ak[jj] + bkv) * 0.0625f);
        vT[(unsigned)t * MSAMP + (j0 + jj)]   = (unsigned short)f2bs(av[jj] + bvv);
    }
}

// ---------------------------------------------------------------------------
// Fused q -> w -> res -> concat. 128-row tile per WG, 4 waves (2 row x 2 col),
// MFMA 16x16x32 bf16 (f32 inputs converted inline). Epilogue stages f32 res
// in LDS and writes coalesced f32 [res | features].
// ---------------------------------------------------------------------------
#define QS  264   // qlds row stride (bf16), pad kills 512B-stride conflicts
#define WSR 136   // wlds row stride (bf16)
#define RS  258   // rlds row stride (f32)
#define MAIN_LDS (128 * RS * 4)   // 132096 B (>= phase-1/2 usage of 102400 B)

__global__ __launch_bounds__(256, 1) void main_kernel(
    const float* __restrict__ feat,
    const float* __restrict__ Wq, const float* __restrict__ bq,
    const unsigned short* __restrict__ k_s,
    const unsigned short* __restrict__ vT,
    float* __restrict__ out)
{
    extern __shared__ char smem[];
    unsigned short* qlds = (unsigned short*)smem;
    unsigned short* wlds = (unsigned short*)(smem + 128 * QS * 2);

    const int tid  = threadIdx.x;
    const int ln   = tid & 63;
    const int wid  = tid >> 6;
    const int wr   = wid & 1;
    const int wc   = wid >> 1;
    const int r0   = blockIdx.x * 128;
    const int lrow = ln & 15;
    const int lk   = (ln >> 4) * 8;
    const int crow = (ln >> 4) * 4;

    const f32x4_t fzero = {0.f, 0.f, 0.f, 0.f};

    // ---- phase 1: q = feat @ Wq^T + bq -> bf16 in qlds ----
    f32x4_t qa[4][8];
#pragma unroll
    for (int m = 0; m < 4; m++)
#pragma unroll
        for (int n = 0; n < 8; n++) qa[m][n] = fzero;

#pragma unroll
    for (int kb = 0; kb < DMODEL; kb += 32) {
        bf16x8_t A[4], B[8];
#pragma unroll
        for (int m = 0; m < 4; m++)
            A[m] = cvt8(feat + (size_t)(r0 + wr * 64 + m * 16 + lrow) * DMODEL + kb + lk);
#pragma unroll
        for (int n = 0; n < 8; n++)
            B[n] = cvt8(Wq + (size_t)(wc * 128 + n * 16 + lrow) * DMODEL + kb + lk);
#pragma unroll
        for (int m = 0; m < 4; m++)
#pragma unroll
            for (int n = 0; n < 8; n++)
                qa[m][n] = __builtin_amdgcn_mfma_f32_16x16x32_bf16(
                    A[m], B[n], qa[m][n], 0, 0, 0);
    }
#pragma unroll
    for (int n = 0; n < 8; n++) {
        float bqv = bq[wc * 128 + n * 16 + lrow];
#pragma unroll
        for (int m = 0; m < 4; m++)
#pragma unroll
            for (int r = 0; r < 4; r++)
                qlds[(wr * 64 + m * 16 + crow + r) * QS + wc * 128 + n * 16 + lrow] =
                    (unsigned short)f2bs(qa[m][n][r] + bqv);
    }
    __syncthreads();

    // ---- phase 2: flash-style w-chunk -> res accumulation ----
    f32x4_t racc[4][8];
#pragma unroll
    for (int m = 0; m < 4; m++)
#pragma unroll
        for (int n = 0; n < 8; n++) racc[m][n] = fzero;

    for (int jb = 0; jb < 8; jb++) {
        f32x4_t wa[4][4];
#pragma unroll
        for (int m = 0; m < 4; m++)
#pragma unroll
            for (int n = 0; n < 4; n++) wa[m][n] = fzero;

#pragma unroll
        for (int kb = 0; kb < DMODEL; kb += 32) {
            bf16x8_t A[4], B[4];
#pragma unroll
            for (int m = 0; m < 4; m++)
                A[m] = *(const bf16x8_t*)(qlds +
                    (wr * 64 + m * 16 + lrow) * QS + kb + lk);
#pragma unroll
            for (int n = 0; n < 4; n++)
                B[n] = *(const bf16x8_t*)(k_s +
                    (size_t)(jb * 128 + wc * 64 + n * 16 + lrow) * DMODEL + kb + lk);
#pragma unroll
            for (int m = 0; m < 4; m++)
#pragma unroll
                for (int n = 0; n < 4; n++)
                    wa[m][n] = __builtin_amdgcn_mfma_f32_16x16x32_bf16(
                        A[m], B[n], wa[m][n], 0, 0, 0);
        }
#pragma unroll
        for (int m = 0; m < 4; m++)
#pragma unroll
            for (int n = 0; n < 4; n++)
#pragma unroll
                for (int r = 0; r < 4; r++)
                    wlds[(wr * 64 + m * 16 + crow + r) * WSR + wc * 64 + n * 16 + lrow] =
                        (unsigned short)f2bs(wa[m][n][r]);
        __syncthreads();

#pragma unroll
        for (int kb2 = 0; kb2 < 128; kb2 += 32) {
            bf16x8_t A[4], B[8];
#pragma unroll
            for (int m = 0; m < 4; m++)
                A[m] = *(const bf16x8_t*)(wlds +
                    (wr * 64 + m * 16 + lrow) * WSR + kb2 + lk);
#pragma unroll
            for (int n = 0; n < 8; n++)
                B[n] = *(const bf16x8_t*)(vT +
                    (size_t)(wc * 128 + n * 16 + lrow) * MSAMP + jb * 128 + kb2 + lk);
#pragma unroll
            for (int m = 0; m < 4; m++)
#pragma unroll
                for (int n = 0; n < 8; n++)
                    racc[m][n] = __builtin_amdgcn_mfma_f32_16x16x32_bf16(
                        A[m], B[n], racc[m][n], 0, 0, 0);
        }
        __syncthreads();
    }

    // ---- phase 3: epilogue, f32 res -> LDS, coalesced f32 [res|feat] store ----
    float* rlds = (float*)smem;   // qlds/wlds dead now
#pragma unroll
    for (int m = 0; m < 4; m++)
#pragma unroll
        for (int n = 0; n < 8; n++)
#pragma unroll
            for (int r = 0; r < 4; r++)
                rlds[(wr * 64 + m * 16 + crow + r) * RS + wc * 128 + n * 16 + lrow] =
                    racc[m][n][r];
    __syncthreads();

#pragma unroll
    for (int base = 0; base < 128; base += 4) {
        int row = base + wid;
        f32x4_t a = *(const f32x4_t*)(rlds + row * RS + ln * 4);
        f32x4_t b = *(const f32x4_t*)(feat + (size_t)(r0 + row) * DMODEL + ln * 4);
        *(f32x4_t*)(out + (size_t)(r0 + row) * 512 + ln * 4)       = a;
        *(f32x4_t*)(out + (size_t)(r0 + row) * 512 + 256 + ln * 4) = b;
    }
}

// ---------------------------------------------------------------------------
extern "C" void kernel_launch(void* const* d_in, const int* in_sizes, int n_in,
                              void* d_out, int out_size, void* d_ws, size_t ws_size,
                              hipStream_t stream) {
    const float* p_xyz = (const float*)d_in[0];
    const float* feat  = (const float*)d_in[1];
    const float* Wq    = (const float*)d_in[2];
    const float* bq    = (const float*)d_in[3];
    const float* Wk    = (const float*)d_in[4];
    const float* bk    = (const float*)d_in[5];
    const float* Wv    = (const float*)d_in[6];
    const float* bv    = (const float*)d_in[7];
    float* out = (float*)d_out;

    char* ws = (char*)d_ws;
    unsigned long long* slots = (unsigned long long*)ws;                //   4 KB [2][NW][4]
    int*                idx   = (int*)(ws + 8192);                      //   4 KB
    unsigned short*     k_s   = (unsigned short*)(ws + 16384);          // 512 KB
    unsigned short*     vT    = (unsigned short*)(ws + 16384 + 524288); // 512 KB

    hipMemsetAsync(d_ws, 0, 4096, stream);   // invalidate slots every call

    hipLaunchKernelGGL(fps_kernel, dim3(NW), dim3(64), 0, stream,
                       p_xyz, slots, idx);
    hipLaunchKernelGGL(kv_kernel, dim3(MSAMP / 4), dim3(256), 0, stream,
                       feat, Wk, bk, Wv, bv, idx, k_s, vT);
    hipFuncSetAttribute((const void*)main_kernel,
                        hipFuncAttributeMaxDynamicSharedMemorySize, MAIN_LDS);
    hipLaunchKernelGGL(main_kernel, dim3(N_PTS / 128), dim3(256), MAIN_LDS, stream,
                       feat, Wq, bq, k_s, vT, out);
}